// Round 1
// baseline (595.641 us; speedup 1.0000x reference)
//
#include <hip/hip_runtime.h>

// GCN: 3x GCNConv(128) + classifier(40) on N=50000 nodes, E=800000 edges.
// Strategy: build CSR (dst-sorted) per call in workspace, then per-layer:
//   GEMM (fp32, LDS-tiled)  ->  gather-aggregate (block-per-node, no atomics)
// Self-loops folded in analytically.

#define FEAT 128

// ---------------- CSR build ----------------

__global__ __launch_bounds__(256) void k_degree(const int* __restrict__ dst,
                                                int* __restrict__ deg, int E) {
  int e = blockIdx.x * 256 + threadIdx.x;
  if (e < E) atomicAdd(&deg[dst[e]], 1);
}

__global__ __launch_bounds__(256) void k_dinv(const int* __restrict__ deg,
                                              float* __restrict__ dinv, int N) {
  int i = blockIdx.x * 256 + threadIdx.x;
  if (i < N) dinv[i] = rsqrtf((float)(deg[i] + 1));  // +1 = self loop
}

__global__ __launch_bounds__(256) void k_scanA(const int* __restrict__ deg,
                                               int* __restrict__ partial, int N) {
  __shared__ int s[256];
  int t = threadIdx.x;
  int i = blockIdx.x * 256 + t;
  s[t] = (i < N) ? deg[i] : 0;
  __syncthreads();
  for (int off = 128; off > 0; off >>= 1) {
    if (t < off) s[t] += s[t + off];
    __syncthreads();
  }
  if (t == 0) partial[blockIdx.x] = s[0];
}

// single block: exclusive scan of per-block sums (nblk <= 256)
__global__ __launch_bounds__(256) void k_scanB(int* __restrict__ partial, int nblk,
                                               int* __restrict__ offsets, int N) {
  __shared__ int s[256];
  int t = threadIdx.x;
  int v = (t < nblk) ? partial[t] : 0;
  s[t] = v;
  __syncthreads();
  for (int off = 1; off < 256; off <<= 1) {
    int x = (t >= off) ? s[t - off] : 0;
    __syncthreads();
    s[t] += x;
    __syncthreads();
  }
  if (t < nblk) partial[t] = s[t] - v;   // exclusive prefix
  if (t == 0) offsets[N] = s[255];       // total == E
}

__global__ __launch_bounds__(256) void k_scanC(const int* __restrict__ deg,
                                               const int* __restrict__ partial,
                                               int* __restrict__ offsets, int N) {
  __shared__ int s[256];
  int t = threadIdx.x;
  int i = blockIdx.x * 256 + t;
  int v = (i < N) ? deg[i] : 0;
  s[t] = v;
  __syncthreads();
  for (int off = 1; off < 256; off <<= 1) {
    int x = (t >= off) ? s[t - off] : 0;
    __syncthreads();
    s[t] += x;
    __syncthreads();
  }
  if (i < N) offsets[i] = partial[blockIdx.x] + s[t] - v;
}

__global__ __launch_bounds__(256) void k_scatter(const int* __restrict__ src,
                                                 const int* __restrict__ dst,
                                                 const int* __restrict__ offsets,
                                                 int* __restrict__ cursor,
                                                 int* __restrict__ col, int E) {
  int e = blockIdx.x * 256 + threadIdx.x;
  if (e < E) {
    int d = dst[e];
    int pos = offsets[d] + atomicAdd(&cursor[d], 1);
    col[pos] = src[e];
  }
}

// ---------------- dense layers ----------------

// C[nrows,128] = A[nrows,128] @ W[128,128], fp32. 16 rows/block, W staged in
// LDS in two K-halves (stay under 64KB static LDS).
__global__ __launch_bounds__(256) void k_gemm128(const float* __restrict__ A,
                                                 const float* __restrict__ W,
                                                 float* __restrict__ C, int nrows) {
  __shared__ float sW[64 * 128];  // 32 KB
  __shared__ float sA[16 * 128];  // 8 KB
  int t = threadIdx.x;
  int rowBase = blockIdx.x * 16;
  int rowsHere = min(16, nrows - rowBase);

  const float4* A4 = (const float4*)(A + (size_t)rowBase * FEAT);
  float4* sA4 = (float4*)sA;
  for (int i = t; i < rowsHere * 32; i += 256) sA4[i] = A4[i];

  float acc[8] = {0.f, 0.f, 0.f, 0.f, 0.f, 0.f, 0.f, 0.f};
  int r = t >> 4;
  int c0 = (t & 15) * 8;

  for (int half = 0; half < 2; ++half) {
    __syncthreads();  // also covers sA on first pass; protects sW reuse after
    const float4* W4 = (const float4*)(W + half * 64 * FEAT);
    float4* sW4 = (float4*)sW;
    for (int i = t; i < 2048; i += 256) sW4[i] = W4[i];
    __syncthreads();
    int kbase = half * 64;
    #pragma unroll 4
    for (int k = 0; k < 64; ++k) {
      float a = sA[r * FEAT + kbase + k];
      float4 w0 = *(const float4*)&sW[k * FEAT + c0];
      float4 w1 = *(const float4*)&sW[k * FEAT + c0 + 4];
      acc[0] += a * w0.x; acc[1] += a * w0.y; acc[2] += a * w0.z; acc[3] += a * w0.w;
      acc[4] += a * w1.x; acc[5] += a * w1.y; acc[6] += a * w1.z; acc[7] += a * w1.w;
    }
  }

  if (r < rowsHere) {
    float4* Crow = (float4*)(C + ((size_t)(rowBase + r)) * FEAT + c0);
    Crow[0] = make_float4(acc[0], acc[1], acc[2], acc[3]);
    Crow[1] = make_float4(acc[4], acc[5], acc[6], acc[7]);
  }
}

// out[node,t] = relu( sum_{e in CSR[node]} dinv[node]*dinv[src]*hw[src,t]
//                    + dinv[node]^2 * hw[node,t] + bias[t] )
__global__ __launch_bounds__(128) void k_aggregate(const float* __restrict__ hw,
                                                   const int* __restrict__ offsets,
                                                   const int* __restrict__ col,
                                                   const float* __restrict__ dinv,
                                                   const float* __restrict__ bias,
                                                   float* __restrict__ out,
                                                   int doRelu) {
  int node = blockIdx.x;
  int t = threadIdx.x;
  float di = dinv[node];
  float acc = di * di * hw[(size_t)node * FEAT + t];
  int e0 = offsets[node], e1 = offsets[node + 1];
  for (int e = e0; e < e1; ++e) {
    int s = col[e];
    float nrm = di * dinv[s];
    acc += nrm * hw[(size_t)s * FEAT + t];
  }
  acc += bias[t];
  if (doRelu) acc = fmaxf(acc, 0.f);
  out[(size_t)node * FEAT + t] = acc;
}

// logits[N,40] = h[N,128] @ Wc[128,40] + bc
__global__ __launch_bounds__(256) void k_classifier(const float* __restrict__ h,
                                                    const float* __restrict__ Wc,
                                                    const float* __restrict__ bc,
                                                    float* __restrict__ out, int N) {
  __shared__ float sW[128 * 40];  // 20 KB
  int t = threadIdx.x;
  for (int i = t; i < 128 * 40; i += 256) sW[i] = Wc[i];
  __syncthreads();
  int total = N * 40;
  for (int idx = blockIdx.x * 256 + t; idx < total; idx += gridDim.x * 256) {
    int r = idx / 40;
    int c = idx - r * 40;
    const float* hr = h + (size_t)r * FEAT;
    float acc = bc[c];
    #pragma unroll 8
    for (int k = 0; k < FEAT; ++k) acc += hr[k] * sW[k * 40 + c];
    out[idx] = acc;
  }
}

// ---------------- launch ----------------

extern "C" void kernel_launch(void* const* d_in, const int* in_sizes, int n_in,
                              void* d_out, int out_size, void* d_ws, size_t ws_size,
                              hipStream_t stream) {
  const float* x    = (const float*)d_in[0];
  const int*   edge = (const int*)d_in[1];
  const float* W1   = (const float*)d_in[2];
  const float* b1   = (const float*)d_in[3];
  const float* W2   = (const float*)d_in[4];
  const float* b2   = (const float*)d_in[5];
  const float* W3   = (const float*)d_in[6];
  const float* b3   = (const float*)d_in[7];
  const float* Wc   = (const float*)d_in[8];
  const float* bc   = (const float*)d_in[9];

  int N = in_sizes[0] / FEAT;
  int E = in_sizes[1] / 2;

  float* out  = (float*)d_out;
  float* hOut = out + (size_t)N * 40;  // second output lives here; layer-3 writes it

  // workspace carve-up (256B aligned slabs)
  size_t o = 0;
  char* wsb = (char*)d_ws;
  auto take = [&](size_t bytes) -> void* {
    void* p = wsb + o;
    o += (bytes + 255) & ~(size_t)255;
    return p;
  };
  float* dinv    = (float*)take((size_t)N * 4);
  int*   deg     = (int*)take((size_t)N * 4);
  int*   cursor  = (int*)take((size_t)N * 4);
  int*   partial = (int*)take(256 * 4);
  int*   offsets = (int*)take(((size_t)N + 8) * 4);
  int*   col     = (int*)take((size_t)E * 4);
  float* T       = (float*)take((size_t)N * FEAT * 4);  // h @ W
  float* B       = (float*)take((size_t)N * FEAT * 4);  // layer output

  const int* e_src = edge;
  const int* e_dst = edge + E;

  hipMemsetAsync(deg, 0, (size_t)N * 4, stream);
  hipMemsetAsync(cursor, 0, (size_t)N * 4, stream);

  int nblk = (N + 255) / 256;
  int eblk = (E + 255) / 256;

  k_degree<<<eblk, 256, 0, stream>>>(e_dst, deg, E);
  k_dinv<<<nblk, 256, 0, stream>>>(deg, dinv, N);
  k_scanA<<<nblk, 256, 0, stream>>>(deg, partial, N);
  k_scanB<<<1, 256, 0, stream>>>(partial, nblk, offsets, N);
  k_scanC<<<nblk, 256, 0, stream>>>(deg, partial, offsets, N);
  k_scatter<<<eblk, 256, 0, stream>>>(e_src, e_dst, offsets, cursor, col, E);

  int gblk = (N + 15) / 16;
  // layer 1
  k_gemm128<<<gblk, 256, 0, stream>>>(x, W1, T, N);
  k_aggregate<<<N, 128, 0, stream>>>(T, offsets, col, dinv, b1, B, 1);
  // layer 2
  k_gemm128<<<gblk, 256, 0, stream>>>(B, W2, T, N);
  k_aggregate<<<N, 128, 0, stream>>>(T, offsets, col, dinv, b2, B, 1);
  // layer 3 -> h output region
  k_gemm128<<<gblk, 256, 0, stream>>>(B, W3, T, N);
  k_aggregate<<<N, 128, 0, stream>>>(T, offsets, col, dinv, b3, hOut, 1);
  // classifier head
  k_classifier<<<2048, 256, 0, stream>>>(hOut, Wc, bc, out, N);
}

// Round 2
// 398.152 us; speedup vs baseline: 1.4960x; 1.4960x over previous
//
#include <hip/hip_runtime.h>

// GCN: 3x GCNConv(128) + classifier(40) on N=50000, E=800000.
// CSR built per call; per layer: fp32 GEMM (reg-blocked, dinv-scaled epilogue)
// -> gather-aggregate (block-per-node, 8-way unrolled, no atomics).

#define FEAT 128

// ---------------- CSR build ----------------

__global__ __launch_bounds__(256) void k_degree(const int* __restrict__ dst,
                                                int* __restrict__ deg, int E) {
  int e = blockIdx.x * 256 + threadIdx.x;
  if (e < E) atomicAdd(&deg[dst[e]], 1);
}

__global__ __launch_bounds__(256) void k_scanA(const int* __restrict__ deg,
                                               int* __restrict__ partial, int N) {
  __shared__ int s[256];
  int t = threadIdx.x;
  int i = blockIdx.x * 256 + t;
  s[t] = (i < N) ? deg[i] : 0;
  __syncthreads();
  for (int off = 128; off > 0; off >>= 1) {
    if (t < off) s[t] += s[t + off];
    __syncthreads();
  }
  if (t == 0) partial[blockIdx.x] = s[0];
}

// single block: exclusive scan of per-block sums (nblk <= 256)
__global__ __launch_bounds__(256) void k_scanB(int* __restrict__ partial, int nblk,
                                               int* __restrict__ offsets, int N) {
  __shared__ int s[256];
  int t = threadIdx.x;
  int v = (t < nblk) ? partial[t] : 0;
  s[t] = v;
  __syncthreads();
  for (int off = 1; off < 256; off <<= 1) {
    int x = (t >= off) ? s[t - off] : 0;
    __syncthreads();
    s[t] += x;
    __syncthreads();
  }
  if (t < nblk) partial[t] = s[t] - v;   // exclusive prefix
  if (t == 0) offsets[N] = s[255];       // total == E
}

// per-element exclusive scan + fused dinv
__global__ __launch_bounds__(256) void k_scanC(const int* __restrict__ deg,
                                               const int* __restrict__ partial,
                                               int* __restrict__ offsets,
                                               float* __restrict__ dinv, int N) {
  __shared__ int s[256];
  int t = threadIdx.x;
  int i = blockIdx.x * 256 + t;
  int v = (i < N) ? deg[i] : 0;
  s[t] = v;
  __syncthreads();
  for (int off = 1; off < 256; off <<= 1) {
    int x = (t >= off) ? s[t - off] : 0;
    __syncthreads();
    s[t] += x;
    __syncthreads();
  }
  if (i < N) {
    offsets[i] = partial[blockIdx.x] + s[t] - v;
    dinv[i] = rsqrtf((float)(v + 1));  // +1 = self loop
  }
}

__global__ __launch_bounds__(256) void k_scatter(const int* __restrict__ src,
                                                 const int* __restrict__ dst,
                                                 const int* __restrict__ offsets,
                                                 int* __restrict__ cursor,
                                                 int* __restrict__ col, int E) {
  int e = blockIdx.x * 256 + threadIdx.x;
  if (e < E) {
    int d = dst[e];
    int pos = offsets[d] + atomicAdd(&cursor[d], 1);
    col[pos] = src[e];
  }
}

// ---------------- dense layers ----------------

// C[r][c] = dinv[r] * sum_k A[r][k]*W[k][c].  64 rows/block, 256 threads,
// each thread computes 4 rows x 8 cols (VALU-bound: 32 FMA per 6 LDS reads).
__global__ __launch_bounds__(256) void k_gemm128(const float* __restrict__ A,
                                                 const float* __restrict__ W,
                                                 const float* __restrict__ dinv,
                                                 float* __restrict__ C, int nrows) {
  __shared__ float sA[64 * 132];   // [row][k], stride 132 to dodge bank conflicts
  __shared__ float sW[32 * 128];   // quarter of W, [k][c]
  int t = threadIdx.x;
  int rowBase = blockIdx.x * 64;
  int rowsHere = min(64, nrows - rowBase);

  {  // stage A (coalesced float4), zero-fill tail rows
    const float4* A4 = (const float4*)(A + (size_t)rowBase * FEAT);
    #pragma unroll
    for (int i = 0; i < 8; ++i) {
      int lin = t + i * 256;          // float4 index over 64x32
      int r = lin >> 5, kc = lin & 31;
      float4 v = make_float4(0.f, 0.f, 0.f, 0.f);
      if (r < rowsHere) v = A4[lin];
      *(float4*)&sA[r * 132 + kc * 4] = v;
    }
  }

  float acc[4][8];
  #pragma unroll
  for (int i = 0; i < 4; ++i)
    #pragma unroll
    for (int j = 0; j < 8; ++j) acc[i][j] = 0.f;

  int rg = (t >> 4) * 4;       // base row of this thread's 4 rows
  int c0 = (t & 15) * 8;       // base col of this thread's 8 cols

  for (int q = 0; q < 4; ++q) {
    __syncthreads();
    {  // stage quarter of W
      const float4* W4 = (const float4*)(W + q * 32 * FEAT);
      float4* sW4 = (float4*)sW;
      #pragma unroll
      for (int i = 0; i < 4; ++i) sW4[t + i * 256] = W4[t + i * 256];
    }
    __syncthreads();
    int kb = q * 32;
    #pragma unroll 8
    for (int kk = 0; kk < 32; ++kk) {
      int k = kb + kk;
      float a0 = sA[(rg + 0) * 132 + k];
      float a1 = sA[(rg + 1) * 132 + k];
      float a2 = sA[(rg + 2) * 132 + k];
      float a3 = sA[(rg + 3) * 132 + k];
      const float* wrow = &sW[kk * FEAT + c0];
      float4 w0 = *(const float4*)wrow;
      float4 w1 = *(const float4*)(wrow + 4);
      acc[0][0] += a0 * w0.x; acc[0][1] += a0 * w0.y; acc[0][2] += a0 * w0.z; acc[0][3] += a0 * w0.w;
      acc[0][4] += a0 * w1.x; acc[0][5] += a0 * w1.y; acc[0][6] += a0 * w1.z; acc[0][7] += a0 * w1.w;
      acc[1][0] += a1 * w0.x; acc[1][1] += a1 * w0.y; acc[1][2] += a1 * w0.z; acc[1][3] += a1 * w0.w;
      acc[1][4] += a1 * w1.x; acc[1][5] += a1 * w1.y; acc[1][6] += a1 * w1.z; acc[1][7] += a1 * w1.w;
      acc[2][0] += a2 * w0.x; acc[2][1] += a2 * w0.y; acc[2][2] += a2 * w0.z; acc[2][3] += a2 * w0.w;
      acc[2][4] += a2 * w1.x; acc[2][5] += a2 * w1.y; acc[2][6] += a2 * w1.z; acc[2][7] += a2 * w1.w;
      acc[3][0] += a3 * w0.x; acc[3][1] += a3 * w0.y; acc[3][2] += a3 * w0.z; acc[3][3] += a3 * w0.w;
      acc[3][4] += a3 * w1.x; acc[3][5] += a3 * w1.y; acc[3][6] += a3 * w1.z; acc[3][7] += a3 * w1.w;
    }
  }

  #pragma unroll
  for (int i = 0; i < 4; ++i) {
    int r = rg + i;
    if (r < rowsHere) {
      float s = dinv[rowBase + r];
      float4 o0 = make_float4(acc[i][0] * s, acc[i][1] * s, acc[i][2] * s, acc[i][3] * s);
      float4 o1 = make_float4(acc[i][4] * s, acc[i][5] * s, acc[i][6] * s, acc[i][7] * s);
      float4* Crow = (float4*)(C + (size_t)(rowBase + r) * FEAT + c0);
      Crow[0] = o0;
      Crow[1] = o1;
    }
  }
}

// Tp is pre-scaled by dinv[row]. out[d][t] = relu(dinv[d]*(sum_e Tp[col[e]][t]
// + Tp[d][t]) + bias[t]).  8-way unrolled edge loop -> 8 outstanding gathers.
__global__ __launch_bounds__(128) void k_aggregate(const float* __restrict__ Tp,
                                                   const int* __restrict__ offsets,
                                                   const int* __restrict__ col,
                                                   const float* __restrict__ dinv,
                                                   const float* __restrict__ bias,
                                                   float* __restrict__ out,
                                                   int doRelu) {
  int node = blockIdx.x;
  int t = threadIdx.x;
  int e0 = offsets[node], e1 = offsets[node + 1];
  float acc = Tp[(size_t)node * FEAT + t];  // self loop
  int e = e0;
  for (; e + 8 <= e1; e += 8) {
    int s0 = col[e + 0], s1 = col[e + 1], s2 = col[e + 2], s3 = col[e + 3];
    int s4 = col[e + 4], s5 = col[e + 5], s6 = col[e + 6], s7 = col[e + 7];
    float v0 = Tp[(size_t)s0 * FEAT + t];
    float v1 = Tp[(size_t)s1 * FEAT + t];
    float v2 = Tp[(size_t)s2 * FEAT + t];
    float v3 = Tp[(size_t)s3 * FEAT + t];
    float v4 = Tp[(size_t)s4 * FEAT + t];
    float v5 = Tp[(size_t)s5 * FEAT + t];
    float v6 = Tp[(size_t)s6 * FEAT + t];
    float v7 = Tp[(size_t)s7 * FEAT + t];
    acc += ((v0 + v1) + (v2 + v3)) + ((v4 + v5) + (v6 + v7));
  }
  for (; e + 2 <= e1; e += 2) {
    float v0 = Tp[(size_t)col[e] * FEAT + t];
    float v1 = Tp[(size_t)col[e + 1] * FEAT + t];
    acc += v0 + v1;
  }
  if (e < e1) acc += Tp[(size_t)col[e] * FEAT + t];
  acc = dinv[node] * acc + bias[t];
  if (doRelu) acc = fmaxf(acc, 0.f);
  out[(size_t)node * FEAT + t] = acc;
}

// logits[N,40] = h[N,128] @ Wc[128,40] + bc.  64 nodes/block; thread handles
// 2 nodes x 5 classes from LDS (h staged coalesced, Wc transposed+padded).
__global__ __launch_bounds__(256) void k_classifier(const float* __restrict__ h,
                                                    const float* __restrict__ Wc,
                                                    const float* __restrict__ bc,
                                                    float* __restrict__ out, int N) {
  __shared__ float sh[64 * 132];    // [node][k] padded
  __shared__ float sWt[40 * 130];   // [c][k] padded
  int t = threadIdx.x;
  int nodeBase = blockIdx.x * 64;
  int nodesHere = min(64, N - nodeBase);

  for (int i = t; i < FEAT * 40; i += 256) {
    int k = i / 40, c = i - k * 40;
    sWt[c * 130 + k] = Wc[i];
  }
  {
    const float4* H4 = (const float4*)(h + (size_t)nodeBase * FEAT);
    #pragma unroll
    for (int i = 0; i < 8; ++i) {
      int lin = t + i * 256;
      int r = lin >> 5, kc = lin & 31;
      float4 v = make_float4(0.f, 0.f, 0.f, 0.f);
      if (r < nodesHere) v = H4[lin];
      *(float4*)&sh[r * 132 + kc * 4] = v;
    }
  }
  __syncthreads();

  int n0 = (t >> 3) * 2;      // this thread's 2 nodes
  int cg = (t & 7) * 5;       // this thread's 5 classes
  float acc0[5], acc1[5];
  #pragma unroll
  for (int j = 0; j < 5; ++j) { acc0[j] = bc[cg + j]; acc1[j] = acc0[j]; }

  #pragma unroll 4
  for (int k4 = 0; k4 < 32; ++k4) {
    float4 h0 = *(const float4*)&sh[n0 * 132 + k4 * 4];
    float4 h1 = *(const float4*)&sh[(n0 + 1) * 132 + k4 * 4];
    #pragma unroll
    for (int j = 0; j < 5; ++j) {
      float4 w = *(const float4*)&sWt[(cg + j) * 130 + k4 * 4];
      acc0[j] += h0.x * w.x + h0.y * w.y + h0.z * w.z + h0.w * w.w;
      acc1[j] += h1.x * w.x + h1.y * w.y + h1.z * w.z + h1.w * w.w;
    }
  }

  if (n0 < nodesHere) {
    float* o = out + (size_t)(nodeBase + n0) * 40 + cg;
    #pragma unroll
    for (int j = 0; j < 5; ++j) o[j] = acc0[j];
  }
  if (n0 + 1 < nodesHere) {
    float* o = out + (size_t)(nodeBase + n0 + 1) * 40 + cg;
    #pragma unroll
    for (int j = 0; j < 5; ++j) o[j] = acc1[j];
  }
}

// ---------------- launch ----------------

extern "C" void kernel_launch(void* const* d_in, const int* in_sizes, int n_in,
                              void* d_out, int out_size, void* d_ws, size_t ws_size,
                              hipStream_t stream) {
  const float* x    = (const float*)d_in[0];
  const int*   edge = (const int*)d_in[1];
  const float* W1   = (const float*)d_in[2];
  const float* b1   = (const float*)d_in[3];
  const float* W2   = (const float*)d_in[4];
  const float* b2   = (const float*)d_in[5];
  const float* W3   = (const float*)d_in[6];
  const float* b3   = (const float*)d_in[7];
  const float* Wc   = (const float*)d_in[8];
  const float* bc   = (const float*)d_in[9];

  int N = in_sizes[0] / FEAT;
  int E = in_sizes[1] / 2;

  float* out  = (float*)d_out;
  float* hOut = out + (size_t)N * 40;  // second output; layer-3 aggregate writes it

  size_t o = 0;
  char* wsb = (char*)d_ws;
  auto take = [&](size_t bytes) -> void* {
    void* p = wsb + o;
    o += (bytes + 255) & ~(size_t)255;
    return p;
  };
  float* dinv    = (float*)take((size_t)N * 4);
  int*   degcur  = (int*)take((size_t)2 * N * 4);  // deg | cursor, one memset
  int*   deg     = degcur;
  int*   cursor  = degcur + N;
  int*   partial = (int*)take(256 * 4);
  int*   offsets = (int*)take(((size_t)N + 8) * 4);
  int*   col     = (int*)take((size_t)E * 4);
  float* T       = (float*)take((size_t)N * FEAT * 4);  // dinv-scaled h@W
  float* B       = (float*)take((size_t)N * FEAT * 4);  // layer output

  const int* e_src = edge;
  const int* e_dst = edge + E;

  hipMemsetAsync(degcur, 0, (size_t)2 * N * 4, stream);

  int nblk = (N + 255) / 256;
  int eblk = (E + 255) / 256;

  k_degree<<<eblk, 256, 0, stream>>>(e_dst, deg, E);
  k_scanA<<<nblk, 256, 0, stream>>>(deg, partial, N);
  k_scanB<<<1, 256, 0, stream>>>(partial, nblk, offsets, N);
  k_scanC<<<nblk, 256, 0, stream>>>(deg, partial, offsets, dinv, N);
  k_scatter<<<eblk, 256, 0, stream>>>(e_src, e_dst, offsets, cursor, col, E);

  int gblk = (N + 63) / 64;
  // layer 1
  k_gemm128<<<gblk, 256, 0, stream>>>(x, W1, dinv, T, N);
  k_aggregate<<<N, 128, 0, stream>>>(T, offsets, col, dinv, b1, B, 1);
  // layer 2
  k_gemm128<<<gblk, 256, 0, stream>>>(B, W2, dinv, T, N);
  k_aggregate<<<N, 128, 0, stream>>>(T, offsets, col, dinv, b2, B, 1);
  // layer 3 -> h output region
  k_gemm128<<<gblk, 256, 0, stream>>>(B, W3, dinv, T, N);
  k_aggregate<<<N, 128, 0, stream>>>(T, offsets, col, dinv, b3, hOut, 1);
  // classifier head
  k_classifier<<<gblk, 256, 0, stream>>>(hOut, Wc, bc, out, N);
}

// Round 3
// 353.874 us; speedup vs baseline: 1.6832x; 1.1251x over previous
//
#include <hip/hip_runtime.h>
#include <hip/hip_fp16.h>

// GCN: 3x GCNConv(128) + classifier(40) on N=50000, E=800000.
// CSR per call; per layer: fp32 GEMM (reg-blocked, pipelined W staging,
// dinv-scaled fp16 epilogue) -> gather-aggregate over fp16 table (1 wave/node,
// half2 lanes, 8-deep gather ILP, fp32 accumulation).

#define FEAT 128

// ---------------- CSR build ----------------

__global__ __launch_bounds__(256) void k_degree(const int* __restrict__ dst,
                                                int* __restrict__ deg, int E) {
  int e = blockIdx.x * 256 + threadIdx.x;
  if (e < E) atomicAdd(&deg[dst[e]], 1);
}

__global__ __launch_bounds__(256) void k_scanA(const int* __restrict__ deg,
                                               int* __restrict__ partial, int N) {
  __shared__ int s[256];
  int t = threadIdx.x;
  int i = blockIdx.x * 256 + t;
  s[t] = (i < N) ? deg[i] : 0;
  __syncthreads();
  for (int off = 128; off > 0; off >>= 1) {
    if (t < off) s[t] += s[t + off];
    __syncthreads();
  }
  if (t == 0) partial[blockIdx.x] = s[0];
}

// single block: exclusive scan of per-block sums (nblk <= 256)
__global__ __launch_bounds__(256) void k_scanB(int* __restrict__ partial, int nblk,
                                               int* __restrict__ offsets, int N) {
  __shared__ int s[256];
  int t = threadIdx.x;
  int v = (t < nblk) ? partial[t] : 0;
  s[t] = v;
  __syncthreads();
  for (int off = 1; off < 256; off <<= 1) {
    int x = (t >= off) ? s[t - off] : 0;
    __syncthreads();
    s[t] += x;
    __syncthreads();
  }
  if (t < nblk) partial[t] = s[t] - v;   // exclusive prefix
  if (t == 0) offsets[N] = s[255];       // total == E
}

// per-element exclusive scan + fused dinv
__global__ __launch_bounds__(256) void k_scanC(const int* __restrict__ deg,
                                               const int* __restrict__ partial,
                                               int* __restrict__ offsets,
                                               float* __restrict__ dinv, int N) {
  __shared__ int s[256];
  int t = threadIdx.x;
  int i = blockIdx.x * 256 + t;
  int v = (i < N) ? deg[i] : 0;
  s[t] = v;
  __syncthreads();
  for (int off = 1; off < 256; off <<= 1) {
    int x = (t >= off) ? s[t - off] : 0;
    __syncthreads();
    s[t] += x;
    __syncthreads();
  }
  if (i < N) {
    offsets[i] = partial[blockIdx.x] + s[t] - v;
    dinv[i] = rsqrtf((float)(v + 1));  // +1 = self loop
  }
}

__global__ __launch_bounds__(256) void k_scatter(const int* __restrict__ src,
                                                 const int* __restrict__ dst,
                                                 const int* __restrict__ offsets,
                                                 int* __restrict__ cursor,
                                                 int* __restrict__ col, int E) {
  int e = blockIdx.x * 256 + threadIdx.x;
  if (e < E) {
    int d = dst[e];
    int pos = offsets[d] + atomicAdd(&cursor[d], 1);
    col[pos] = src[e];
  }
}

// ---------------- dense layers ----------------

__device__ inline unsigned pack2h(float a, float b) {
  __half2 h = __floats2half2_rn(a, b);
  return *(unsigned*)&h;
}

// T[r][c] = half( dinv[r] * sum_k A[r][k]*W[k][c] ).  64 rows/block, 256 thr,
// thread: 4 rows x cols {c0..c0+3, c0+64..c0+67} (2-way LDS access = free).
// W quarter staged in LDS, next quarter preloaded to regs under the FMAs.
__global__ __launch_bounds__(256) void k_gemm128(const float* __restrict__ A,
                                                 const float* __restrict__ W,
                                                 const float* __restrict__ dinv,
                                                 __half2* __restrict__ T2,
                                                 int nrows) {
  __shared__ float sA[64 * 128];   // 32 KB, [row][k] (A-reads are broadcasts)
  __shared__ float sW[32 * 128];   // 16 KB, quarter of W, [k][c]
  int t = threadIdx.x;
  int rowBase = blockIdx.x * 64;
  int rowsHere = min(64, nrows - rowBase);

  {  // stage A (coalesced float4), zero-fill tail rows
    const float4* A4 = (const float4*)(A + (size_t)rowBase * FEAT);
    #pragma unroll
    for (int i = 0; i < 8; ++i) {
      int lin = t + i * 256;          // float4 index over 64x32
      float4 v = make_float4(0.f, 0.f, 0.f, 0.f);
      if ((lin >> 5) < rowsHere) v = A4[lin];
      ((float4*)sA)[lin] = v;
    }
  }

  // preload W quarter 0 into registers
  float4 wreg[4];
  {
    const float4* W4 = (const float4*)W;
    #pragma unroll
    for (int i = 0; i < 4; ++i) wreg[i] = W4[t + i * 256];
  }

  float acc[4][8];
  #pragma unroll
  for (int i = 0; i < 4; ++i)
    #pragma unroll
    for (int j = 0; j < 8; ++j) acc[i][j] = 0.f;

  int rg = (t >> 4) * 4;       // base row of this thread's 4 rows
  int c0 = (t & 15) * 4;       // cols c0..c0+3 and c0+64..c0+67

  for (int q = 0; q < 4; ++q) {
    __syncthreads();  // q=0: sA ready; q>0: previous sW fully consumed
    #pragma unroll
    for (int i = 0; i < 4; ++i) ((float4*)sW)[t + i * 256] = wreg[i];
    __syncthreads();
    if (q < 3) {  // issue next quarter's global loads; consumed after inner loop
      const float4* W4 = (const float4*)(W + (q + 1) * 32 * FEAT);
      #pragma unroll
      for (int i = 0; i < 4; ++i) wreg[i] = W4[t + i * 256];
    }
    int kb = q * 32;
    #pragma unroll 16
    for (int kk = 0; kk < 32; ++kk) {
      float a0 = sA[(rg + 0) * FEAT + kb + kk];
      float a1 = sA[(rg + 1) * FEAT + kb + kk];
      float a2 = sA[(rg + 2) * FEAT + kb + kk];
      float a3 = sA[(rg + 3) * FEAT + kb + kk];
      const float* wr = &sW[kk * FEAT];
      float4 w0 = *(const float4*)(wr + c0);
      float4 w1 = *(const float4*)(wr + c0 + 64);
      acc[0][0] += a0 * w0.x; acc[0][1] += a0 * w0.y; acc[0][2] += a0 * w0.z; acc[0][3] += a0 * w0.w;
      acc[0][4] += a0 * w1.x; acc[0][5] += a0 * w1.y; acc[0][6] += a0 * w1.z; acc[0][7] += a0 * w1.w;
      acc[1][0] += a1 * w0.x; acc[1][1] += a1 * w0.y; acc[1][2] += a1 * w0.z; acc[1][3] += a1 * w0.w;
      acc[1][4] += a1 * w1.x; acc[1][5] += a1 * w1.y; acc[1][6] += a1 * w1.z; acc[1][7] += a1 * w1.w;
      acc[2][0] += a2 * w0.x; acc[2][1] += a2 * w0.y; acc[2][2] += a2 * w0.z; acc[2][3] += a2 * w0.w;
      acc[2][4] += a2 * w1.x; acc[2][5] += a2 * w1.y; acc[2][6] += a2 * w1.z; acc[2][7] += a2 * w1.w;
      acc[3][0] += a3 * w0.x; acc[3][1] += a3 * w0.y; acc[3][2] += a3 * w0.z; acc[3][3] += a3 * w0.w;
      acc[3][4] += a3 * w1.x; acc[3][5] += a3 * w1.y; acc[3][6] += a3 * w1.z; acc[3][7] += a3 * w1.w;
    }
  }

  #pragma unroll
  for (int i = 0; i < 4; ++i) {
    int r = rg + i;
    if (r < rowsHere) {
      float s = dinv[rowBase + r];
      uint2 p0, p1;
      p0.x = pack2h(acc[i][0] * s, acc[i][1] * s);
      p0.y = pack2h(acc[i][2] * s, acc[i][3] * s);
      p1.x = pack2h(acc[i][4] * s, acc[i][5] * s);
      p1.y = pack2h(acc[i][6] * s, acc[i][7] * s);
      __half2* row = T2 + (size_t)(rowBase + r) * 64;
      *(uint2*)(row + (c0 >> 1)) = p0;
      *(uint2*)(row + ((c0 + 64) >> 1)) = p1;
    }
  }
}

// T2 rows pre-scaled by dinv[src]. One wave per node; lane owns features
// {2*lane, 2*lane+1}. out[d] = relu(dinv[d]*(self + sum_e T2[col[e]]) + bias).
__global__ __launch_bounds__(256) void k_aggregate(const __half2* __restrict__ T2,
                                                   const int* __restrict__ offsets,
                                                   const int* __restrict__ col,
                                                   const float* __restrict__ dinv,
                                                   const float* __restrict__ bias,
                                                   float* __restrict__ out,
                                                   int doRelu, int N) {
  int wave = threadIdx.x >> 6;
  int lane = threadIdx.x & 63;
  int node = blockIdx.x * 4 + wave;
  if (node >= N) return;
  int e0 = offsets[node], e1 = offsets[node + 1];

  __half2 sv = T2[(size_t)node * 64 + lane];  // self loop
  float ax = __half2float(sv.x), ay = __half2float(sv.y);

  int e = e0;
  for (; e + 8 <= e1; e += 8) {
    int s0 = col[e + 0], s1 = col[e + 1], s2 = col[e + 2], s3 = col[e + 3];
    int s4 = col[e + 4], s5 = col[e + 5], s6 = col[e + 6], s7 = col[e + 7];
    __half2 v0 = T2[(size_t)s0 * 64 + lane];
    __half2 v1 = T2[(size_t)s1 * 64 + lane];
    __half2 v2 = T2[(size_t)s2 * 64 + lane];
    __half2 v3 = T2[(size_t)s3 * 64 + lane];
    __half2 v4 = T2[(size_t)s4 * 64 + lane];
    __half2 v5 = T2[(size_t)s5 * 64 + lane];
    __half2 v6 = T2[(size_t)s6 * 64 + lane];
    __half2 v7 = T2[(size_t)s7 * 64 + lane];
    float x01 = __half2float(v0.x) + __half2float(v1.x);
    float x23 = __half2float(v2.x) + __half2float(v3.x);
    float x45 = __half2float(v4.x) + __half2float(v5.x);
    float x67 = __half2float(v6.x) + __half2float(v7.x);
    float y01 = __half2float(v0.y) + __half2float(v1.y);
    float y23 = __half2float(v2.y) + __half2float(v3.y);
    float y45 = __half2float(v4.y) + __half2float(v5.y);
    float y67 = __half2float(v6.y) + __half2float(v7.y);
    ax += (x01 + x23) + (x45 + x67);
    ay += (y01 + y23) + (y45 + y67);
  }
  for (; e + 2 <= e1; e += 2) {
    __half2 v0 = T2[(size_t)col[e] * 64 + lane];
    __half2 v1 = T2[(size_t)col[e + 1] * 64 + lane];
    ax += __half2float(v0.x) + __half2float(v1.x);
    ay += __half2float(v0.y) + __half2float(v1.y);
  }
  if (e < e1) {
    __half2 v = T2[(size_t)col[e] * 64 + lane];
    ax += __half2float(v.x);
    ay += __half2float(v.y);
  }

  float di = dinv[node];
  float2 b = ((const float2*)bias)[lane];
  float ox = di * ax + b.x;
  float oy = di * ay + b.y;
  if (doRelu) { ox = fmaxf(ox, 0.f); oy = fmaxf(oy, 0.f); }
  float2 o = make_float2(ox, oy);
  *(float2*)&out[(size_t)node * FEAT + 2 * lane] = o;
}

// logits[N,40] = h[N,128] @ Wc[128,40] + bc.  64 nodes/block; thread handles
// 2 nodes x 5 classes from LDS (h staged coalesced, Wc transposed+padded).
__global__ __launch_bounds__(256) void k_classifier(const float* __restrict__ h,
                                                    const float* __restrict__ Wc,
                                                    const float* __restrict__ bc,
                                                    float* __restrict__ out, int N) {
  __shared__ float sh[64 * 132];    // [node][k] padded
  __shared__ float sWt[40 * 130];   // [c][k] padded
  int t = threadIdx.x;
  int nodeBase = blockIdx.x * 64;
  int nodesHere = min(64, N - nodeBase);

  for (int i = t; i < FEAT * 40; i += 256) {
    int k = i / 40, c = i - k * 40;
    sWt[c * 130 + k] = Wc[i];
  }
  {
    const float4* H4 = (const float4*)(h + (size_t)nodeBase * FEAT);
    #pragma unroll
    for (int i = 0; i < 8; ++i) {
      int lin = t + i * 256;
      int r = lin >> 5, kc = lin & 31;
      float4 v = make_float4(0.f, 0.f, 0.f, 0.f);
      if (r < nodesHere) v = H4[lin];
      *(float4*)&sh[r * 132 + kc * 4] = v;
    }
  }
  __syncthreads();

  int n0 = (t >> 3) * 2;      // this thread's 2 nodes
  int cg = (t & 7) * 5;       // this thread's 5 classes
  float acc0[5], acc1[5];
  #pragma unroll
  for (int j = 0; j < 5; ++j) { acc0[j] = bc[cg + j]; acc1[j] = acc0[j]; }

  #pragma unroll 4
  for (int k4 = 0; k4 < 32; ++k4) {
    float4 h0 = *(const float4*)&sh[n0 * 132 + k4 * 4];
    float4 h1 = *(const float4*)&sh[(n0 + 1) * 132 + k4 * 4];
    #pragma unroll
    for (int j = 0; j < 5; ++j) {
      float4 w = *(const float4*)&sWt[(cg + j) * 130 + k4 * 4];
      acc0[j] += h0.x * w.x + h0.y * w.y + h0.z * w.z + h0.w * w.w;
      acc1[j] += h1.x * w.x + h1.y * w.y + h1.z * w.z + h1.w * w.w;
    }
  }

  if (n0 < nodesHere) {
    float* o = out + (size_t)(nodeBase + n0) * 40 + cg;
    #pragma unroll
    for (int j = 0; j < 5; ++j) o[j] = acc0[j];
  }
  if (n0 + 1 < nodesHere) {
    float* o = out + (size_t)(nodeBase + n0 + 1) * 40 + cg;
    #pragma unroll
    for (int j = 0; j < 5; ++j) o[j] = acc1[j];
  }
}

// ---------------- launch ----------------

extern "C" void kernel_launch(void* const* d_in, const int* in_sizes, int n_in,
                              void* d_out, int out_size, void* d_ws, size_t ws_size,
                              hipStream_t stream) {
  const float* x    = (const float*)d_in[0];
  const int*   edge = (const int*)d_in[1];
  const float* W1   = (const float*)d_in[2];
  const float* b1   = (const float*)d_in[3];
  const float* W2   = (const float*)d_in[4];
  const float* b2   = (const float*)d_in[5];
  const float* W3   = (const float*)d_in[6];
  const float* b3   = (const float*)d_in[7];
  const float* Wc   = (const float*)d_in[8];
  const float* bc   = (const float*)d_in[9];

  int N = in_sizes[0] / FEAT;
  int E = in_sizes[1] / 2;

  float* out  = (float*)d_out;
  float* hOut = out + (size_t)N * 40;  // second output; layer-3 aggregate writes it

  size_t o = 0;
  char* wsb = (char*)d_ws;
  auto take = [&](size_t bytes) -> void* {
    void* p = wsb + o;
    o += (bytes + 255) & ~(size_t)255;
    return p;
  };
  float*   dinv    = (float*)take((size_t)N * 4);
  int*     degcur  = (int*)take((size_t)2 * N * 4);  // deg | cursor, one memset
  int*     deg     = degcur;
  int*     cursor  = degcur + N;
  int*     partial = (int*)take(256 * 4);
  int*     offsets = (int*)take(((size_t)N + 8) * 4);
  int*     col     = (int*)take((size_t)E * 4);
  __half2* T2      = (__half2*)take((size_t)N * 64 * 4);  // fp16 dinv-scaled h@W
  float*   B       = (float*)take((size_t)N * FEAT * 4);  // layer output (fp32)

  const int* e_src = edge;
  const int* e_dst = edge + E;

  hipMemsetAsync(degcur, 0, (size_t)2 * N * 4, stream);

  int nblk = (N + 255) / 256;
  int eblk = (E + 255) / 256;

  k_degree<<<eblk, 256, 0, stream>>>(e_dst, deg, E);
  k_scanA<<<nblk, 256, 0, stream>>>(deg, partial, N);
  k_scanB<<<1, 256, 0, stream>>>(partial, nblk, offsets, N);
  k_scanC<<<nblk, 256, 0, stream>>>(deg, partial, offsets, dinv, N);
  k_scatter<<<eblk, 256, 0, stream>>>(e_src, e_dst, offsets, cursor, col, E);

  int gblk = (N + 63) / 64;
  int ablk = (N + 3) / 4;
  // layer 1
  k_gemm128<<<gblk, 256, 0, stream>>>(x, W1, dinv, T2, N);
  k_aggregate<<<ablk, 256, 0, stream>>>(T2, offsets, col, dinv, b1, B, 1, N);
  // layer 2
  k_gemm128<<<gblk, 256, 0, stream>>>(B, W2, dinv, T2, N);
  k_aggregate<<<ablk, 256, 0, stream>>>(T2, offsets, col, dinv, b2, B, 1, N);
  // layer 3 -> h output region
  k_gemm128<<<gblk, 256, 0, stream>>>(B, W3, dinv, T2, N);
  k_aggregate<<<ablk, 256, 0, stream>>>(T2, offsets, col, dinv, b3, hOut, 1, N);
  // classifier head
  k_classifier<<<gblk, 256, 0, stream>>>(hOut, Wc, bc, out, N);
}

// Round 4
// 245.575 us; speedup vs baseline: 2.4255x; 1.4410x over previous
//
#include <hip/hip_runtime.h>
#include <hip/hip_fp16.h>

// GCN: 3x GCNConv(128) + classifier(40) on N=50000, E=800000.
// CSR per call (rank-split, no scatter atomic chain); per layer:
//   fp16 MFMA GEMM (32x32x16, LDS XOR-swizzled, dinv-scaled fp16 epilogue)
//   -> gather-aggregate over fp16 table (1 wave/node, fp32 accumulation).

#define FEAT 128

typedef _Float16 half_t;
typedef _Float16 f16x8 __attribute__((ext_vector_type(8)));
typedef float f32x16 __attribute__((ext_vector_type(16)));

// ---------------- CSR build ----------------

// deg count + per-edge rank (atomic return), stores have no dependent consumer
__global__ __launch_bounds__(256) void k_count_rank(const int* __restrict__ dst,
                                                    int* __restrict__ deg,
                                                    int* __restrict__ rank, int E) {
  int e = blockIdx.x * 256 + threadIdx.x;
  if (e < E) rank[e] = atomicAdd(&deg[dst[e]], 1);
}

__global__ __launch_bounds__(256) void k_scanA(const int* __restrict__ deg,
                                               int* __restrict__ partial, int N) {
  __shared__ int s[256];
  int t = threadIdx.x;
  int i = blockIdx.x * 256 + t;
  s[t] = (i < N) ? deg[i] : 0;
  __syncthreads();
  for (int off = 128; off > 0; off >>= 1) {
    if (t < off) s[t] += s[t + off];
    __syncthreads();
  }
  if (t == 0) partial[blockIdx.x] = s[0];
}

// single block: exclusive scan of per-block sums (nblk <= 256)
__global__ __launch_bounds__(256) void k_scanB(int* __restrict__ partial, int nblk,
                                               int* __restrict__ offsets, int N) {
  __shared__ int s[256];
  int t = threadIdx.x;
  int v = (t < nblk) ? partial[t] : 0;
  s[t] = v;
  __syncthreads();
  for (int off = 1; off < 256; off <<= 1) {
    int x = (t >= off) ? s[t - off] : 0;
    __syncthreads();
    s[t] += x;
    __syncthreads();
  }
  if (t < nblk) partial[t] = s[t] - v;   // exclusive prefix
  if (t == 0) offsets[N] = s[255];       // total == E
}

// per-element exclusive scan + fused dinv
__global__ __launch_bounds__(256) void k_scanC(const int* __restrict__ deg,
                                               const int* __restrict__ partial,
                                               int* __restrict__ offsets,
                                               float* __restrict__ dinv, int N) {
  __shared__ int s[256];
  int t = threadIdx.x;
  int i = blockIdx.x * 256 + t;
  int v = (i < N) ? deg[i] : 0;
  s[t] = v;
  __syncthreads();
  for (int off = 1; off < 256; off <<= 1) {
    int x = (t >= off) ? s[t - off] : 0;
    __syncthreads();
    s[t] += x;
    __syncthreads();
  }
  if (i < N) {
    offsets[i] = partial[blockIdx.x] + s[t] - v;
    dinv[i] = rsqrtf((float)(v + 1));  // +1 = self loop
  }
}

// no atomics: position = offsets[dst] + rank (from count pass)
__global__ __launch_bounds__(256) void k_place(const int* __restrict__ src,
                                               const int* __restrict__ dst,
                                               const int* __restrict__ offsets,
                                               const int* __restrict__ rank,
                                               int* __restrict__ col, int E) {
  int e = blockIdx.x * 256 + threadIdx.x;
  if (e < E) col[offsets[dst[e]] + rank[e]] = src[e];
}

// ---------------- weight prep: Wt[n][k] = (half)W[k][n], 3 matrices ----------------

__global__ __launch_bounds__(256) void k_prepW(const float* __restrict__ W1,
                                               const float* __restrict__ W2,
                                               const float* __restrict__ W3,
                                               half_t* __restrict__ Wt1,
                                               half_t* __restrict__ Wt2,
                                               half_t* __restrict__ Wt3) {
  int idx = blockIdx.x * 256 + threadIdx.x;  // 0 .. 3*16384
  int which = idx >> 14;
  int i = idx & 16383;
  int k = i >> 7, n = i & 127;
  const float* W = (which == 0) ? W1 : (which == 1) ? W2 : W3;
  half_t* Wt = (which == 0) ? Wt1 : (which == 1) ? Wt2 : Wt3;
  Wt[n * 128 + k] = (half_t)W[i];
}

// ---------------- MFMA GEMM ----------------
// T[r][c] = half( dinv[r] * sum_k A[r][k]*W[k][c] ), A 128-row tile + full Wt
// in LDS (XOR-swizzled rows: byte ^= (row&15)<<4 -> conflict-free b128 frags).
// 128 threads = 2 waves; wave computes 64 rows x 128 cols via 32x32x16 MFMA.
template <int SRC_FP32>
__global__ __launch_bounds__(128) void k_gemm_mfma(const void* __restrict__ Asrc,
                                                   const half_t* __restrict__ Wt,
                                                   const float* __restrict__ dinv,
                                                   half_t* __restrict__ T,
                                                   int nrows) {
  __shared__ char lds[65536];
  char* sA = lds;            // 128 rows x 256 B (fp16), swizzled
  char* sW = lds + 32768;    // 128 cols x 256 B (fp16, [n][k]), swizzled
  int t = threadIdx.x;
  int rowBase = blockIdx.x * 128;
  int rowsHere = min(128, nrows - rowBase);

  // stage Wt (2048 x 16B chunks, coalesced read, swizzled LDS write)
  #pragma unroll
  for (int i = 0; i < 16; ++i) {
    int lin = t + i * 128;
    int r = lin >> 4, c = lin & 15;
    *(float4*)(sW + r * 256 + ((c * 16) ^ ((r & 15) << 4))) =
        *(const float4*)((const char*)Wt + r * 256 + c * 16);
  }
  // stage A
  if (SRC_FP32) {
    const float* Af = (const float*)Asrc;
    #pragma unroll
    for (int i = 0; i < 16; ++i) {
      int lin = t + i * 128;
      int r = lin >> 4, c = lin & 15;
      f16x8 h = {};
      if (r < rowsHere) {
        const float4* p = (const float4*)(Af + (size_t)(rowBase + r) * FEAT + c * 8);
        float4 v0 = p[0], v1 = p[1];
        h[0] = (half_t)v0.x; h[1] = (half_t)v0.y; h[2] = (half_t)v0.z; h[3] = (half_t)v0.w;
        h[4] = (half_t)v1.x; h[5] = (half_t)v1.y; h[6] = (half_t)v1.z; h[7] = (half_t)v1.w;
      }
      *(f16x8*)(sA + r * 256 + ((c * 16) ^ ((r & 15) << 4))) = h;
    }
  } else {
    const char* Ah = (const char*)Asrc;
    #pragma unroll
    for (int i = 0; i < 16; ++i) {
      int lin = t + i * 128;
      int r = lin >> 4, c = lin & 15;
      float4 v = {};
      if (r < rowsHere) v = *(const float4*)(Ah + (size_t)(rowBase + r) * 256 + c * 16);
      *(float4*)(sA + r * 256 + ((c * 16) ^ ((r & 15) << 4))) = v;
    }
  }
  __syncthreads();

  int wv = t >> 6;
  int l = t & 63;
  int l31 = l & 31;
  int lhi = l >> 5;
  int sw = (l31 & 15) << 4;

  f32x16 acc[2][4] = {};

  #pragma unroll
  for (int step = 0; step < 8; ++step) {
    int koff = step * 32 + lhi * 16;   // byte offset of this lane's k-group
    int ko = koff ^ sw;
    f16x8 a0 = *(const f16x8*)(sA + (wv * 64 + l31) * 256 + ko);
    f16x8 a1 = *(const f16x8*)(sA + (wv * 64 + 32 + l31) * 256 + ko);
    f16x8 b0 = *(const f16x8*)(sW + (l31) * 256 + ko);
    f16x8 b1 = *(const f16x8*)(sW + (32 + l31) * 256 + ko);
    f16x8 b2 = *(const f16x8*)(sW + (64 + l31) * 256 + ko);
    f16x8 b3 = *(const f16x8*)(sW + (96 + l31) * 256 + ko);
    acc[0][0] = __builtin_amdgcn_mfma_f32_32x32x16_f16(a0, b0, acc[0][0], 0, 0, 0);
    acc[0][1] = __builtin_amdgcn_mfma_f32_32x32x16_f16(a0, b1, acc[0][1], 0, 0, 0);
    acc[0][2] = __builtin_amdgcn_mfma_f32_32x32x16_f16(a0, b2, acc[0][2], 0, 0, 0);
    acc[0][3] = __builtin_amdgcn_mfma_f32_32x32x16_f16(a0, b3, acc[0][3], 0, 0, 0);
    acc[1][0] = __builtin_amdgcn_mfma_f32_32x32x16_f16(a1, b0, acc[1][0], 0, 0, 0);
    acc[1][1] = __builtin_amdgcn_mfma_f32_32x32x16_f16(a1, b1, acc[1][1], 0, 0, 0);
    acc[1][2] = __builtin_amdgcn_mfma_f32_32x32x16_f16(a1, b2, acc[1][2], 0, 0, 0);
    acc[1][3] = __builtin_amdgcn_mfma_f32_32x32x16_f16(a1, b3, acc[1][3], 0, 0, 0);
  }

  // epilogue: C/D layout col=l&31, row=(j&3)+8*(j>>2)+4*(l>>5)
  #pragma unroll
  for (int m = 0; m < 2; ++m) {
    #pragma unroll
    for (int j = 0; j < 16; ++j) {
      int rloc = wv * 64 + m * 32 + (j & 3) + 8 * (j >> 2) + 4 * lhi;
      if (rloc < rowsHere) {
        int grow = rowBase + rloc;
        float d = dinv[grow];
        #pragma unroll
        for (int n = 0; n < 4; ++n) {
          T[(size_t)grow * FEAT + n * 32 + l31] = (half_t)(acc[m][n][j] * d);
        }
      }
    }
  }
}

// ---------------- aggregate ----------------
// T2 rows pre-scaled by dinv[src]. One wave/node; lane owns features {2l,2l+1}.
// out = relu(dinv[d]*(self + sum_e T2[col[e]]) + bias); fp16 out (layers 1-2)
// or fp32 out (layer 3 -> hOut).
template <int OUTF>
__global__ __launch_bounds__(256) void k_aggregate(const __half2* __restrict__ T2,
                                                   const int* __restrict__ offsets,
                                                   const int* __restrict__ col,
                                                   const float* __restrict__ dinv,
                                                   const float* __restrict__ bias,
                                                   float* __restrict__ outF,
                                                   __half2* __restrict__ outH,
                                                   int N) {
  int wave = threadIdx.x >> 6;
  int lane = threadIdx.x & 63;
  int node = blockIdx.x * 4 + wave;
  if (node >= N) return;
  int e0 = offsets[node], e1 = offsets[node + 1];

  __half2 sv = T2[(size_t)node * 64 + lane];  // self loop
  float ax = __half2float(sv.x), ay = __half2float(sv.y);

  int e = e0;
  for (; e + 8 <= e1; e += 8) {
    int s0 = col[e + 0], s1 = col[e + 1], s2 = col[e + 2], s3 = col[e + 3];
    int s4 = col[e + 4], s5 = col[e + 5], s6 = col[e + 6], s7 = col[e + 7];
    __half2 v0 = T2[(size_t)s0 * 64 + lane];
    __half2 v1 = T2[(size_t)s1 * 64 + lane];
    __half2 v2 = T2[(size_t)s2 * 64 + lane];
    __half2 v3 = T2[(size_t)s3 * 64 + lane];
    __half2 v4 = T2[(size_t)s4 * 64 + lane];
    __half2 v5 = T2[(size_t)s5 * 64 + lane];
    __half2 v6 = T2[(size_t)s6 * 64 + lane];
    __half2 v7 = T2[(size_t)s7 * 64 + lane];
    float x01 = __half2float(v0.x) + __half2float(v1.x);
    float x23 = __half2float(v2.x) + __half2float(v3.x);
    float x45 = __half2float(v4.x) + __half2float(v5.x);
    float x67 = __half2float(v6.x) + __half2float(v7.x);
    float y01 = __half2float(v0.y) + __half2float(v1.y);
    float y23 = __half2float(v2.y) + __half2float(v3.y);
    float y45 = __half2float(v4.y) + __half2float(v5.y);
    float y67 = __half2float(v6.y) + __half2float(v7.y);
    ax += (x01 + x23) + (x45 + x67);
    ay += (y01 + y23) + (y45 + y67);
  }
  for (; e + 2 <= e1; e += 2) {
    __half2 v0 = T2[(size_t)col[e] * 64 + lane];
    __half2 v1 = T2[(size_t)col[e + 1] * 64 + lane];
    ax += __half2float(v0.x) + __half2float(v1.x);
    ay += __half2float(v0.y) + __half2float(v1.y);
  }
  if (e < e1) {
    __half2 v = T2[(size_t)col[e] * 64 + lane];
    ax += __half2float(v.x);
    ay += __half2float(v.y);
  }

  float di = dinv[node];
  float2 b = ((const float2*)bias)[lane];
  float ox = fmaxf(di * ax + b.x, 0.f);
  float oy = fmaxf(di * ay + b.y, 0.f);
  if (OUTF) {
    *(float2*)&outF[(size_t)node * FEAT + 2 * lane] = make_float2(ox, oy);
  } else {
    outH[(size_t)node * 64 + lane] = __floats2half2_rn(ox, oy);
  }
}

// ---------------- classifier ----------------
// logits[N,40] = h[N,128] @ Wc[128,40] + bc.  64 nodes/block.
__global__ __launch_bounds__(256) void k_classifier(const float* __restrict__ h,
                                                    const float* __restrict__ Wc,
                                                    const float* __restrict__ bc,
                                                    float* __restrict__ out, int N) {
  __shared__ float sh[64 * 132];    // [node][k] padded
  __shared__ float sWt[40 * 130];   // [c][k] padded
  int t = threadIdx.x;
  int nodeBase = blockIdx.x * 64;
  int nodesHere = min(64, N - nodeBase);

  for (int i = t; i < FEAT * 40; i += 256) {
    int k = i / 40, c = i - k * 40;
    sWt[c * 130 + k] = Wc[i];
  }
  {
    const float4* H4 = (const float4*)(h + (size_t)nodeBase * FEAT);
    #pragma unroll
    for (int i = 0; i < 8; ++i) {
      int lin = t + i * 256;
      int r = lin >> 5, kc = lin & 31;
      float4 v = make_float4(0.f, 0.f, 0.f, 0.f);
      if (r < nodesHere) v = H4[lin];
      *(float4*)&sh[r * 132 + kc * 4] = v;
    }
  }
  __syncthreads();

  int n0 = (t >> 3) * 2;      // this thread's 2 nodes
  int cg = (t & 7) * 5;       // this thread's 5 classes
  float acc0[5], acc1[5];
  #pragma unroll
  for (int j = 0; j < 5; ++j) { acc0[j] = bc[cg + j]; acc1[j] = acc0[j]; }

  #pragma unroll 4
  for (int k4 = 0; k4 < 32; ++k4) {
    float4 h0 = *(const float4*)&sh[n0 * 132 + k4 * 4];
    float4 h1 = *(const float4*)&sh[(n0 + 1) * 132 + k4 * 4];
    #pragma unroll
    for (int j = 0; j < 5; ++j) {
      float4 w = *(const float4*)&sWt[(cg + j) * 130 + k4 * 4];
      acc0[j] += h0.x * w.x + h0.y * w.y + h0.z * w.z + h0.w * w.w;
      acc1[j] += h1.x * w.x + h1.y * w.y + h1.z * w.z + h1.w * w.w;
    }
  }

  if (n0 < nodesHere) {
    float* o = out + (size_t)(nodeBase + n0) * 40 + cg;
    #pragma unroll
    for (int j = 0; j < 5; ++j) o[j] = acc0[j];
  }
  if (n0 + 1 < nodesHere) {
    float* o = out + (size_t)(nodeBase + n0 + 1) * 40 + cg;
    #pragma unroll
    for (int j = 0; j < 5; ++j) o[j] = acc1[j];
  }
}

// ---------------- launch ----------------

extern "C" void kernel_launch(void* const* d_in, const int* in_sizes, int n_in,
                              void* d_out, int out_size, void* d_ws, size_t ws_size,
                              hipStream_t stream) {
  const float* x    = (const float*)d_in[0];
  const int*   edge = (const int*)d_in[1];
  const float* W1   = (const float*)d_in[2];
  const float* b1   = (const float*)d_in[3];
  const float* W2   = (const float*)d_in[4];
  const float* b2   = (const float*)d_in[5];
  const float* W3   = (const float*)d_in[6];
  const float* b3   = (const float*)d_in[7];
  const float* Wc   = (const float*)d_in[8];
  const float* bc   = (const float*)d_in[9];

  int N = in_sizes[0] / FEAT;
  int E = in_sizes[1] / 2;

  float* out  = (float*)d_out;
  float* hOut = out + (size_t)N * 40;  // second output; layer-3 aggregate writes it

  size_t o = 0;
  char* wsb = (char*)d_ws;
  auto take = [&](size_t bytes) -> void* {
    void* p = wsb + o;
    o += (bytes + 255) & ~(size_t)255;
    return p;
  };
  float*   dinv    = (float*)take((size_t)N * 4);
  int*     deg     = (int*)take((size_t)N * 4);
  int*     rank    = (int*)take((size_t)E * 4);
  int*     partial = (int*)take(256 * 4);
  int*     offsets = (int*)take(((size_t)N + 8) * 4);
  int*     col     = (int*)take((size_t)E * 4);
  half_t*  T2h     = (half_t*)take((size_t)N * FEAT * 2);  // fp16 dinv-scaled h@W
  half_t*  Bh      = (half_t*)take((size_t)N * FEAT * 2);  // fp16 layer activations
  half_t*  Wt1     = (half_t*)take(16384 * 2);
  half_t*  Wt2     = (half_t*)take(16384 * 2);
  half_t*  Wt3     = (half_t*)take(16384 * 2);

  const int* e_src = edge;
  const int* e_dst = edge + E;

  hipMemsetAsync(deg, 0, (size_t)N * 4, stream);

  int nblk = (N + 255) / 256;
  int eblk = (E + 255) / 256;

  k_prepW<<<192, 256, 0, stream>>>(W1, W2, W3, Wt1, Wt2, Wt3);
  k_count_rank<<<eblk, 256, 0, stream>>>(e_dst, deg, rank, E);
  k_scanA<<<nblk, 256, 0, stream>>>(deg, partial, N);
  k_scanB<<<1, 256, 0, stream>>>(partial, nblk, offsets, N);
  k_scanC<<<nblk, 256, 0, stream>>>(deg, partial, offsets, dinv, N);
  k_place<<<eblk, 256, 0, stream>>>(e_src, e_dst, offsets, rank, col, E);

  int gblk = (N + 127) / 128;
  int ablk = (N + 3) / 4;
  __half2* T2 = (__half2*)T2h;
  // layer 1 (fp32 input)
  k_gemm_mfma<1><<<gblk, 128, 0, stream>>>(x, Wt1, dinv, T2h, N);
  k_aggregate<0><<<ablk, 256, 0, stream>>>(T2, offsets, col, dinv, b1, nullptr,
                                           (__half2*)Bh, N);
  // layer 2 (fp16 input)
  k_gemm_mfma<0><<<gblk, 128, 0, stream>>>(Bh, Wt2, dinv, T2h, N);
  k_aggregate<0><<<ablk, 256, 0, stream>>>(T2, offsets, col, dinv, b2, nullptr,
                                           (__half2*)Bh, N);
  // layer 3 -> fp32 h output region
  k_gemm_mfma<0><<<gblk, 128, 0, stream>>>(Bh, Wt3, dinv, T2h, N);
  k_aggregate<1><<<ablk, 256, 0, stream>>>(T2, offsets, col, dinv, b3, hOut,
                                           nullptr, N);
  // classifier head
  k_classifier<<<(N + 63) / 64, 256, 0, stream>>>(hOut, Wc, bc, out, N);
}

// Round 5
// 230.280 us; speedup vs baseline: 2.5866x; 1.0664x over previous
//
#include <hip/hip_runtime.h>
#include <hip/hip_fp16.h>

// GCN: 3x GCNConv(128) + classifier(40) on N=50000, E=800000.
// CSR per call (rank-split, no atomic->store chain, no runtime memset);
// per layer: fp16 MFMA GEMM (32x32x16, XOR-swizzled LDS, dinv-scaled fp16
// epilogue) -> gather-aggregate over fp16 table (2 nodes/wave, 8B/lane,
// 8-deep gather ILP, fp32 accumulation).

#define FEAT 128

typedef _Float16 half_t;
typedef _Float16 f16x8 __attribute__((ext_vector_type(8)));
typedef float f32x16 __attribute__((ext_vector_type(16)));

// ---------------- prep: W transpose->fp16 + deg zero (replaces memset) ----------------

__global__ __launch_bounds__(256) void k_prep(const float* __restrict__ W1,
                                              const float* __restrict__ W2,
                                              const float* __restrict__ W3,
                                              half_t* __restrict__ Wt1,
                                              half_t* __restrict__ Wt2,
                                              half_t* __restrict__ Wt3,
                                              int* __restrict__ deg, int N) {
  int idx = blockIdx.x * 256 + threadIdx.x;
  if (idx < N) deg[idx] = 0;
  if (idx < 3 * 16384) {
    int which = idx >> 14;
    int i = idx & 16383;
    int k = i >> 7, n = i & 127;
    const float* W = (which == 0) ? W1 : (which == 1) ? W2 : W3;
    half_t* Wt = (which == 0) ? Wt1 : (which == 1) ? Wt2 : Wt3;
    Wt[n * 128 + k] = (half_t)W[i];
  }
}

// ---------------- CSR build ----------------

// deg count + per-edge rank (atomic return); stores have no dependent consumer
__global__ __launch_bounds__(256) void k_count_rank(const int* __restrict__ dst,
                                                    int* __restrict__ deg,
                                                    int* __restrict__ rank, int E) {
  int e = blockIdx.x * 256 + threadIdx.x;
  if (e < E) rank[e] = atomicAdd(&deg[dst[e]], 1);
}

__global__ __launch_bounds__(256) void k_scanA(const int* __restrict__ deg,
                                               int* __restrict__ partial, int N) {
  __shared__ int s[256];
  int t = threadIdx.x;
  int i = blockIdx.x * 256 + t;
  s[t] = (i < N) ? deg[i] : 0;
  __syncthreads();
  for (int off = 128; off > 0; off >>= 1) {
    if (t < off) s[t] += s[t + off];
    __syncthreads();
  }
  if (t == 0) partial[blockIdx.x] = s[0];
}

// single block: exclusive scan of per-block sums (nblk <= 256)
__global__ __launch_bounds__(256) void k_scanB(int* __restrict__ partial, int nblk,
                                               int* __restrict__ offsets, int N) {
  __shared__ int s[256];
  int t = threadIdx.x;
  int v = (t < nblk) ? partial[t] : 0;
  s[t] = v;
  __syncthreads();
  for (int off = 1; off < 256; off <<= 1) {
    int x = (t >= off) ? s[t - off] : 0;
    __syncthreads();
    s[t] += x;
    __syncthreads();
  }
  if (t < nblk) partial[t] = s[t] - v;   // exclusive prefix
  if (t == 0) offsets[N] = s[255];       // total == E
}

// per-element exclusive scan + fused dinv
__global__ __launch_bounds__(256) void k_scanC(const int* __restrict__ deg,
                                               const int* __restrict__ partial,
                                               int* __restrict__ offsets,
                                               float* __restrict__ dinv, int N) {
  __shared__ int s[256];
  int t = threadIdx.x;
  int i = blockIdx.x * 256 + t;
  int v = (i < N) ? deg[i] : 0;
  s[t] = v;
  __syncthreads();
  for (int off = 1; off < 256; off <<= 1) {
    int x = (t >= off) ? s[t - off] : 0;
    __syncthreads();
    s[t] += x;
    __syncthreads();
  }
  if (i < N) {
    offsets[i] = partial[blockIdx.x] + s[t] - v;
    dinv[i] = rsqrtf((float)(v + 1));  // +1 = self loop
  }
}

// no atomics: position = offsets[dst] + rank (from count pass)
__global__ __launch_bounds__(256) void k_place(const int* __restrict__ src,
                                               const int* __restrict__ dst,
                                               const int* __restrict__ offsets,
                                               const int* __restrict__ rank,
                                               int* __restrict__ col, int E) {
  int e = blockIdx.x * 256 + threadIdx.x;
  if (e < E) col[offsets[dst[e]] + rank[e]] = src[e];
}

// ---------------- MFMA GEMM ----------------
// T[r][c] = half( dinv[r] * sum_k A[r][k]*W[k][c] ).  128-row tile, full Wt
// in LDS (XOR swizzle byte ^= (row&15)<<4 -> conflict-free b128 frag reads).
// 256 threads = 4 waves; wave computes 32 rows x 128 cols via 32x32x16 MFMA.
template <int SRC_FP32>
__global__ __launch_bounds__(256) void k_gemm_mfma(const void* __restrict__ Asrc,
                                                   const half_t* __restrict__ Wt,
                                                   const float* __restrict__ dinv,
                                                   half_t* __restrict__ T,
                                                   int nrows) {
  __shared__ char lds[65536];
  char* sA = lds;            // 128 rows x 256 B (fp16), swizzled
  char* sW = lds + 32768;    // 128 cols x 256 B (fp16, [n][k]), swizzled
  int t = threadIdx.x;
  int rowBase = blockIdx.x * 128;
  int rowsHere = min(128, nrows - rowBase);

  // stage Wt (2048 x 16B chunks, coalesced read, swizzled LDS write)
  #pragma unroll
  for (int i = 0; i < 8; ++i) {
    int lin = t + i * 256;
    int r = lin >> 4, c = lin & 15;
    *(float4*)(sW + r * 256 + ((c * 16) ^ ((r & 15) << 4))) =
        *(const float4*)((const char*)Wt + r * 256 + c * 16);
  }
  // stage A
  if (SRC_FP32) {
    const float* Af = (const float*)Asrc;
    #pragma unroll
    for (int i = 0; i < 8; ++i) {
      int lin = t + i * 256;
      int r = lin >> 4, c = lin & 15;
      f16x8 h = {};
      if (r < rowsHere) {
        const float4* p = (const float4*)(Af + (size_t)(rowBase + r) * FEAT + c * 8);
        float4 v0 = p[0], v1 = p[1];
        h[0] = (half_t)v0.x; h[1] = (half_t)v0.y; h[2] = (half_t)v0.z; h[3] = (half_t)v0.w;
        h[4] = (half_t)v1.x; h[5] = (half_t)v1.y; h[6] = (half_t)v1.z; h[7] = (half_t)v1.w;
      }
      *(f16x8*)(sA + r * 256 + ((c * 16) ^ ((r & 15) << 4))) = h;
    }
  } else {
    const char* Ah = (const char*)Asrc;
    #pragma unroll
    for (int i = 0; i < 8; ++i) {
      int lin = t + i * 256;
      int r = lin >> 4, c = lin & 15;
      float4 v = {};
      if (r < rowsHere) v = *(const float4*)(Ah + (size_t)(rowBase + r) * 256 + c * 16);
      *(float4*)(sA + r * 256 + ((c * 16) ^ ((r & 15) << 4))) = v;
    }
  }
  __syncthreads();

  int wv = t >> 6;           // wave -> rows [wv*32, wv*32+32)
  int l = t & 63;
  int l31 = l & 31;
  int lhi = l >> 5;
  int sw = (l31 & 15) << 4;

  f32x16 acc[4] = {};

  #pragma unroll
  for (int step = 0; step < 8; ++step) {
    int ko = (step * 32 + lhi * 16) ^ sw;  // this lane's k-group byte offset
    f16x8 a  = *(const f16x8*)(sA + (wv * 32 + l31) * 256 + ko);
    f16x8 b0 = *(const f16x8*)(sW + (l31) * 256 + ko);
    f16x8 b1 = *(const f16x8*)(sW + (32 + l31) * 256 + ko);
    f16x8 b2 = *(const f16x8*)(sW + (64 + l31) * 256 + ko);
    f16x8 b3 = *(const f16x8*)(sW + (96 + l31) * 256 + ko);
    acc[0] = __builtin_amdgcn_mfma_f32_32x32x16_f16(a, b0, acc[0], 0, 0, 0);
    acc[1] = __builtin_amdgcn_mfma_f32_32x32x16_f16(a, b1, acc[1], 0, 0, 0);
    acc[2] = __builtin_amdgcn_mfma_f32_32x32x16_f16(a, b2, acc[2], 0, 0, 0);
    acc[3] = __builtin_amdgcn_mfma_f32_32x32x16_f16(a, b3, acc[3], 0, 0, 0);
  }

  // epilogue: C/D layout col=l&31, row=(j&3)+8*(j>>2)+4*(l>>5)
  #pragma unroll
  for (int j = 0; j < 16; ++j) {
    int rloc = wv * 32 + (j & 3) + 8 * (j >> 2) + 4 * lhi;
    if (rloc < rowsHere) {
      int grow = rowBase + rloc;
      float d = dinv[grow];
      #pragma unroll
      for (int n = 0; n < 4; ++n) {
        T[(size_t)grow * FEAT + n * 32 + l31] = (half_t)(acc[n][j] * d);
      }
    }
  }
}

// ---------------- aggregate ----------------
// T4 rows (256B = 32 uint2 of fp16) pre-scaled by dinv[src]. 2 nodes per wave:
// half-wave (32 lanes) per node, lane owns features {4q..4q+3} (8B loads).
// out = relu(dinv[d]*(self + sum_e row[col[e]]) + bias).
template <int OUTF>
__global__ __launch_bounds__(256) void k_aggregate(const uint2* __restrict__ T4,
                                                   const int* __restrict__ offsets,
                                                   const int* __restrict__ col,
                                                   const float* __restrict__ dinv,
                                                   const float* __restrict__ bias,
                                                   float4* __restrict__ outF,
                                                   uint2* __restrict__ outH,
                                                   int N) {
  int wave = threadIdx.x >> 6;
  int half = (threadIdx.x >> 5) & 1;
  int q = threadIdx.x & 31;              // feature quad index
  int node = (blockIdx.x * 4 + wave) * 2 + half;
  if (node >= N) return;
  int e0 = offsets[node], e1 = offsets[node + 1];

  uint2 sv = T4[(size_t)node * 32 + q];  // self loop
  __half2 h0 = *(__half2*)&sv.x, h1 = *(__half2*)&sv.y;
  float ax = __half2float(h0.x), ay = __half2float(h0.y);
  float az = __half2float(h1.x), aw = __half2float(h1.y);

  int e = e0;
  for (; e + 8 <= e1; e += 8) {
    int s0 = col[e + 0], s1 = col[e + 1], s2 = col[e + 2], s3 = col[e + 3];
    int s4 = col[e + 4], s5 = col[e + 5], s6 = col[e + 6], s7 = col[e + 7];
    uint2 v0 = T4[(size_t)s0 * 32 + q];
    uint2 v1 = T4[(size_t)s1 * 32 + q];
    uint2 v2 = T4[(size_t)s2 * 32 + q];
    uint2 v3 = T4[(size_t)s3 * 32 + q];
    uint2 v4 = T4[(size_t)s4 * 32 + q];
    uint2 v5 = T4[(size_t)s5 * 32 + q];
    uint2 v6 = T4[(size_t)s6 * 32 + q];
    uint2 v7 = T4[(size_t)s7 * 32 + q];
    #pragma unroll
    for (int u = 0; u < 8; ++u) {
      uint2 v = (u == 0) ? v0 : (u == 1) ? v1 : (u == 2) ? v2 : (u == 3) ? v3
              : (u == 4) ? v4 : (u == 5) ? v5 : (u == 6) ? v6 : v7;
      __half2 p0 = *(__half2*)&v.x, p1 = *(__half2*)&v.y;
      ax += __half2float(p0.x); ay += __half2float(p0.y);
      az += __half2float(p1.x); aw += __half2float(p1.y);
    }
  }
  for (; e < e1; ++e) {
    uint2 v = T4[(size_t)col[e] * 32 + q];
    __half2 p0 = *(__half2*)&v.x, p1 = *(__half2*)&v.y;
    ax += __half2float(p0.x); ay += __half2float(p0.y);
    az += __half2float(p1.x); aw += __half2float(p1.y);
  }

  float di = dinv[node];
  float4 b = ((const float4*)bias)[q];
  float ox = fmaxf(di * ax + b.x, 0.f);
  float oy = fmaxf(di * ay + b.y, 0.f);
  float oz = fmaxf(di * az + b.z, 0.f);
  float ow = fmaxf(di * aw + b.w, 0.f);
  if (OUTF) {
    outF[(size_t)node * 32 + q] = make_float4(ox, oy, oz, ow);
  } else {
    uint2 o;
    __half2 t0 = __floats2half2_rn(ox, oy), t1 = __floats2half2_rn(oz, ow);
    o.x = *(unsigned*)&t0; o.y = *(unsigned*)&t1;
    outH[(size_t)node * 32 + q] = o;
  }
}

// ---------------- classifier ----------------
// logits[N,40] = h[N,128] @ Wc[128,40] + bc.  64 nodes/block.
__global__ __launch_bounds__(256) void k_classifier(const float* __restrict__ h,
                                                    const float* __restrict__ Wc,
                                                    const float* __restrict__ bc,
                                                    float* __restrict__ out, int N) {
  __shared__ float sh[64 * 132];    // [node][k] padded
  __shared__ float sWt[40 * 130];   // [c][k] padded
  int t = threadIdx.x;
  int nodeBase = blockIdx.x * 64;
  int nodesHere = min(64, N - nodeBase);

  for (int i = t; i < FEAT * 40; i += 256) {
    int k = i / 40, c = i - k * 40;
    sWt[c * 130 + k] = Wc[i];
  }
  {
    const float4* H4 = (const float4*)(h + (size_t)nodeBase * FEAT);
    #pragma unroll
    for (int i = 0; i < 8; ++i) {
      int lin = t + i * 256;
      int r = lin >> 5, kc = lin & 31;
      float4 v = make_float4(0.f, 0.f, 0.f, 0.f);
      if (r < nodesHere) v = H4[lin];
      *(float4*)&sh[r * 132 + kc * 4] = v;
    }
  }
  __syncthreads();

  int n0 = (t >> 3) * 2;      // this thread's 2 nodes
  int cg = (t & 7) * 5;       // this thread's 5 classes
  float acc0[5], acc1[5];
  #pragma unroll
  for (int j = 0; j < 5; ++j) { acc0[j] = bc[cg + j]; acc1[j] = acc0[j]; }

  #pragma unroll 4
  for (int k4 = 0; k4 < 32; ++k4) {
    float4 h0 = *(const float4*)&sh[n0 * 132 + k4 * 4];
    float4 h1 = *(const float4*)&sh[(n0 + 1) * 132 + k4 * 4];
    #pragma unroll
    for (int j = 0; j < 5; ++j) {
      float4 w = *(const float4*)&sWt[(cg + j) * 130 + k4 * 4];
      acc0[j] += h0.x * w.x + h0.y * w.y + h0.z * w.z + h0.w * w.w;
      acc1[j] += h1.x * w.x + h1.y * w.y + h1.z * w.z + h1.w * w.w;
    }
  }

  if (n0 < nodesHere) {
    float* o = out + (size_t)(nodeBase + n0) * 40 + cg;
    #pragma unroll
    for (int j = 0; j < 5; ++j) o[j] = acc0[j];
  }
  if (n0 + 1 < nodesHere) {
    float* o = out + (size_t)(nodeBase + n0 + 1) * 40 + cg;
    #pragma unroll
    for (int j = 0; j < 5; ++j) o[j] = acc1[j];
  }
}

// ---------------- launch ----------------

extern "C" void kernel_launch(void* const* d_in, const int* in_sizes, int n_in,
                              void* d_out, int out_size, void* d_ws, size_t ws_size,
                              hipStream_t stream) {
  const float* x    = (const float*)d_in[0];
  const int*   edge = (const int*)d_in[1];
  const float* W1   = (const float*)d_in[2];
  const float* b1   = (const float*)d_in[3];
  const float* W2   = (const float*)d_in[4];
  const float* b2   = (const float*)d_in[5];
  const float* W3   = (const float*)d_in[6];
  const float* b3   = (const float*)d_in[7];
  const float* Wc   = (const float*)d_in[8];
  const float* bc   = (const float*)d_in[9];

  int N = in_sizes[0] / FEAT;
  int E = in_sizes[1] / 2;

  float* out  = (float*)d_out;
  float* hOut = out + (size_t)N * 40;  // second output; layer-3 aggregate writes it

  size_t o = 0;
  char* wsb = (char*)d_ws;
  auto take = [&](size_t bytes) -> void* {
    void* p = wsb + o;
    o += (bytes + 255) & ~(size_t)255;
    return p;
  };
  float*   dinv    = (float*)take((size_t)N * 4);
  int*     deg     = (int*)take((size_t)N * 4);
  int*     rank    = (int*)take((size_t)E * 4);
  int*     partial = (int*)take(256 * 4);
  int*     offsets = (int*)take(((size_t)N + 8) * 4);
  int*     col     = (int*)take((size_t)E * 4);
  half_t*  T2h     = (half_t*)take((size_t)N * FEAT * 2);  // fp16 dinv-scaled h@W
  half_t*  Bh      = (half_t*)take((size_t)N * FEAT * 2);  // fp16 layer activations
  half_t*  Wt1     = (half_t*)take(16384 * 2);
  half_t*  Wt2     = (half_t*)take(16384 * 2);
  half_t*  Wt3     = (half_t*)take(16384 * 2);

  const int* e_src = edge;
  const int* e_dst = edge + E;

  int nblk = (N + 255) / 256;
  int eblk = (E + 255) / 256;

  k_prep<<<nblk, 256, 0, stream>>>(W1, W2, W3, Wt1, Wt2, Wt3, deg, N);
  k_count_rank<<<eblk, 256, 0, stream>>>(e_dst, deg, rank, E);
  k_scanA<<<nblk, 256, 0, stream>>>(deg, partial, N);
  k_scanB<<<1, 256, 0, stream>>>(partial, nblk, offsets, N);
  k_scanC<<<nblk, 256, 0, stream>>>(deg, partial, offsets, dinv, N);
  k_place<<<eblk, 256, 0, stream>>>(e_src, e_dst, offsets, rank, col, E);

  int gblk = (N + 127) / 128;
  int ablk = (N + 7) / 8;
  uint2* T4 = (uint2*)T2h;
  // layer 1 (fp32 input)
  k_gemm_mfma<1><<<gblk, 256, 0, stream>>>(x, Wt1, dinv, T2h, N);
  k_aggregate<0><<<ablk, 256, 0, stream>>>(T4, offsets, col, dinv, b1, nullptr,
                                           (uint2*)Bh, N);
  // layer 2 (fp16 input)
  k_gemm_mfma<0><<<gblk, 256, 0, stream>>>(Bh, Wt2, dinv, T2h, N);
  k_aggregate<0><<<ablk, 256, 0, stream>>>(T4, offsets, col, dinv, b2, nullptr,
                                           (uint2*)Bh, N);
  // layer 3 -> fp32 h output region
  k_gemm_mfma<0><<<gblk, 256, 0, stream>>>(Bh, Wt3, dinv, T2h, N);
  k_aggregate<1><<<ablk, 256, 0, stream>>>(T4, offsets, col, dinv, b3,
                                           (float4*)hOut, nullptr, N);
  // classifier head
  k_classifier<<<(N + 63) / 64, 256, 0, stream>>>(hOut, Wc, bc, out, N);
}